// Round 3
// baseline (92.848 us; speedup 1.0000x reference)
//
#include <hip/hip_runtime.h>
#include <math.h>

// out = (sum(W) - N) / N^2,  W = P_hat P_hat^T (rows L2-normalized)
// Identity: sum(W) = || sum_i p_hat_i ||^2  -> one streaming pass.
//
// Single fused kernel (512 blocks x 256 thr):
//  - wave handles 8 consecutive rows, ILP-batched: 8 float4 loads,
//    8-deep pipelined 6-level shuffle reduce (fp32 norms: error budget in
//    sum(W) units is ~18 abs, fp32 contributes ~1e-2), fp64 s-accumulate.
//  - block reduce in LDS -> 256 fp64 unsafeAtomicAdd into acc[256] (512/addr).
//  - last block (atomic counter) computes ||s||^2 and the epilogue.
// acc + counter zeroed by one hipMemsetAsync (graph-capture legal).

#define NROWS 16384
#define DIM   256
#define TPB   256
#define NB    512   // 2048 waves * 8 rows = 16384

__global__ __launch_bounds__(TPB) void cosreg_fused(const float* __restrict__ pts,
                                                    double* __restrict__ acc,
                                                    unsigned int* __restrict__ counter,
                                                    float* __restrict__ out) {
    const int lane = threadIdx.x & 63;
    const int wid  = threadIdx.x >> 6;
    const int gw   = blockIdx.x * 4 + wid;          // 0..2047

    const float4* src = reinterpret_cast<const float4*>(pts) + (size_t)gw * 8 * 64 + lane;

    float4 v[8];
    float  sq[8];
    #pragma unroll
    for (int i = 0; i < 8; ++i) v[i] = src[(size_t)i * 64];
    #pragma unroll
    for (int i = 0; i < 8; ++i)
        sq[i] = v[i].x*v[i].x + v[i].y*v[i].y + v[i].z*v[i].z + v[i].w*v[i].w;
    #pragma unroll
    for (int m = 1; m < 64; m <<= 1) {
        #pragma unroll
        for (int i = 0; i < 8; ++i) sq[i] += __shfl_xor(sq[i], m, 64);
    }

    double a0 = 0.0, a1 = 0.0, a2 = 0.0, a3 = 0.0;
    #pragma unroll
    for (int i = 0; i < 8; ++i) {
        const float inv = 1.0f / sqrtf(sq[i]);
        a0 += (double)(v[i].x * inv);
        a1 += (double)(v[i].y * inv);
        a2 += (double)(v[i].z * inv);
        a3 += (double)(v[i].w * inv);
    }

    // block reduce: 4 waves -> 256 doubles in LDS
    __shared__ double sblk[DIM];
    sblk[threadIdx.x] = 0.0;
    __syncthreads();
    #pragma unroll
    for (int w = 0; w < 4; ++w) {
        if (wid == w) {
            sblk[lane * 4 + 0] += a0;
            sblk[lane * 4 + 1] += a1;
            sblk[lane * 4 + 2] += a2;
            sblk[lane * 4 + 3] += a3;
        }
        __syncthreads();
    }
    unsafeAtomicAdd(&acc[threadIdx.x], sblk[threadIdx.x]);  // native global_atomic_add_f64

    // last-block epilogue
    __threadfence();
    __shared__ bool last;
    if (threadIdx.x == 0)
        last = (atomicAdd(counter, 1u) == NB - 1u);
    __syncthreads();
    if (!last) return;
    __threadfence();

    double s = __hip_atomic_load(&acc[threadIdx.x], __ATOMIC_RELAXED,
                                 __HIP_MEMORY_SCOPE_AGENT);
    double q = s * s;
    #pragma unroll
    for (int m = 1; m < 64; m <<= 1) q += __shfl_xor(q, m, 64);

    __shared__ double red[TPB / 64];
    if (lane == 0) red[wid] = q;
    __syncthreads();
    if (threadIdx.x == 0) {
        const double tot = red[0] + red[1] + red[2] + red[3];
        const double n = (double)NROWS;
        out[0] = (float)((tot - n) / (n * n));
    }
}

extern "C" void kernel_launch(void* const* d_in, const int* in_sizes, int n_in,
                              void* d_out, int out_size, void* d_ws, size_t ws_size,
                              hipStream_t stream) {
    const float* pts = (const float*)d_in[0];
    float* out = (float*)d_out;

    double* acc = (double*)d_ws;                       // 256 doubles = 2 KiB
    unsigned int* counter = (unsigned int*)((char*)d_ws + DIM * sizeof(double));

    hipMemsetAsync(d_ws, 0, DIM * sizeof(double) + 64, stream);
    cosreg_fused<<<NB, TPB, 0, stream>>>(pts, acc, counter, out);
}

// Round 5
// 72.323 us; speedup vs baseline: 1.2838x; 1.2838x over previous
//
#include <hip/hip_runtime.h>
#include <math.h>

// out = (sum(W) - N) / N^2,  W = P_hat P_hat^T (rows L2-normalized)
// Identity: sum(W) = || sum_i p_hat_i ||^2  -> one streaming pass.
//
// Lesson from round 3: device-scope fp64 atomics (512 adds/address past the
// non-coherent XCD L2s) cost ~22us. Deterministic 2-stage tree instead:
//  k1: 128 blocks x 256 thr; wave owns 32 consecutive rows, 4 batches of
//      ILP-8 {float4 load, fp32 6-level shuffle norm, rsqrt, fp64 accumulate};
//      LDS block-reduce -> partial[blk][256] plain coalesced stores (256 KB).
//  k2: one 1024-thread block: sum 128 partial rows -> s[d], ||s||^2, epilogue.
// No atomics, no memset node, bit-deterministic.

#define NROWS 16384
#define DIM   256
#define TPB   256
#define NB    128   // 512 waves * 32 rows = 16384

__global__ __launch_bounds__(TPB) void cosreg_k1(const float* __restrict__ pts,
                                                 double* __restrict__ partial) {
    const int lane = threadIdx.x & 63;
    const int wid  = threadIdx.x >> 6;
    const int gw   = blockIdx.x * 4 + wid;          // 0..511
    const float4* base = reinterpret_cast<const float4*>(pts)
                       + (size_t)gw * 32 * 64 + lane;

    double a0 = 0.0, a1 = 0.0, a2 = 0.0, a3 = 0.0;

    #pragma unroll
    for (int b = 0; b < 4; ++b) {
        float4 v[8];
        float  sq[8];
        #pragma unroll
        for (int i = 0; i < 8; ++i) v[i] = base[(size_t)(b * 8 + i) * 64];
        #pragma unroll
        for (int i = 0; i < 8; ++i)
            sq[i] = v[i].x*v[i].x + v[i].y*v[i].y + v[i].z*v[i].z + v[i].w*v[i].w;
        #pragma unroll
        for (int m = 1; m < 64; m <<= 1) {
            #pragma unroll
            for (int i = 0; i < 8; ++i) sq[i] += __shfl_xor(sq[i], m, 64);
        }
        #pragma unroll
        for (int i = 0; i < 8; ++i) {
            const float inv = 1.0f / sqrtf(sq[i]);
            a0 += (double)(v[i].x * inv);
            a1 += (double)(v[i].y * inv);
            a2 += (double)(v[i].z * inv);
            a3 += (double)(v[i].w * inv);
        }
    }

    __shared__ double sblk[DIM];
    sblk[threadIdx.x] = 0.0;
    __syncthreads();
    #pragma unroll
    for (int w = 0; w < 4; ++w) {
        if (wid == w) {
            sblk[lane * 4 + 0] += a0;
            sblk[lane * 4 + 1] += a1;
            sblk[lane * 4 + 2] += a2;
            sblk[lane * 4 + 3] += a3;
        }
        __syncthreads();
    }
    partial[(size_t)blockIdx.x * DIM + threadIdx.x] = sblk[threadIdx.x];
}

__global__ __launch_bounds__(1024) void cosreg_k2(const double* __restrict__ partial,
                                                  float* __restrict__ out) {
    const int t = threadIdx.x;
    const int d = t & (DIM - 1);
    const int g = t >> 8;                 // 0..3

    double s = 0.0;
    #pragma unroll 8
    for (int b = g; b < NB; b += 4) s += partial[(size_t)b * DIM + d];

    __shared__ double sacc[4][DIM];
    __shared__ double red[4];
    sacc[g][d] = s;
    __syncthreads();

    if (t < DIM) {
        const double sd = sacc[0][t] + sacc[1][t] + sacc[2][t] + sacc[3][t];
        double q = sd * sd;
        #pragma unroll
        for (int m = 1; m < 64; m <<= 1) q += __shfl_xor(q, m, 64);
        if ((t & 63) == 0) red[t >> 6] = q;
    }
    __syncthreads();
    if (t == 0) {
        const double tot = red[0] + red[1] + red[2] + red[3];
        const double n = (double)NROWS;
        out[0] = (float)((tot - n) / (n * n));
    }
}

extern "C" void kernel_launch(void* const* d_in, const int* in_sizes, int n_in,
                              void* d_out, int out_size, void* d_ws, size_t ws_size,
                              hipStream_t stream) {
    const float* pts = (const float*)d_in[0];
    float* out = (float*)d_out;
    double* partial = (double*)d_ws;      // NB*DIM*8 = 256 KiB

    cosreg_k1<<<NB, TPB, 0, stream>>>(pts, partial);
    cosreg_k2<<<1, 1024, 0, stream>>>(partial, out);
}